// Round 3
// baseline (246.570 us; speedup 1.0000x reference)
//
#include <hip/hip_runtime.h>
#include <math.h>

#define V 32768
#define D 15
#define DM 1024
#define B 8
#define T 1024
#define NNODES (V - 1)  // 32767
#define R 4             // rows per wave

// Kernel 1: sig[v*B + b] = sigmoid(dot(W[v], x[b]) + bias[v]) for all internal nodes v.
// Block = 256 threads (4 waves), R=4 rows/wave -> 16 rows/block, grid = 2048.
// K split across 64 lanes (4 float4 each). x staged in LDS (32 KB); per k-step the
// 8 x-float4 are read once and reused across 4 W rows. Row-tail clamp hoisted into
// per-row base pointers (no per-iteration cndmask). ~95 VGPRs -> 4 waves/EU.
__global__ __launch_bounds__(256, 4) void hsm_logits_kernel(
    const float* __restrict__ x,     // [B][DM]
    const float* __restrict__ W,     // [NNODES][DM]
    const float* __restrict__ bias,  // [NNODES]
    float* __restrict__ sig)         // [NNODES][B]
{
    __shared__ float4 xs[B * DM / 4];  // 2048 float4 = 32 KB, xs[b*256 + u]

    const float4* x4 = (const float4*)x;
    #pragma unroll
    for (int i = threadIdx.x; i < B * DM / 4; i += 256) xs[i] = x4[i];
    __syncthreads();

    const int wave = threadIdx.x >> 6;
    const int lane = threadIdx.x & 63;
    const int row0 = (blockIdx.x * 4 + wave) * R;

    const float4* Wb = (const float4*)W;
    const float4* Wr[R];
    #pragma unroll
    for (int r = 0; r < R; r++) {
        int row = row0 + r;
        if (row > NNODES - 1) row = NNODES - 1;  // clamp (hoisted; store guarded below)
        Wr[r] = Wb + (size_t)row * 256;
    }

    float acc[R * B];  // acc[r*8+b]
    #pragma unroll
    for (int i = 0; i < R * B; i++) acc[i] = 0.f;

    // 256 float4 per row; lane covers u = j*64 + lane for j=0..3.
    #pragma unroll
    for (int j = 0; j < 4; j++) {
        const int u = j * 64 + lane;
        float4 wv[R];
        #pragma unroll
        for (int r = 0; r < R; r++) wv[r] = Wr[r][u];
        float4 xv[B];
        #pragma unroll
        for (int b = 0; b < B; b++) xv[b] = xs[b * 256 + u];
        #pragma unroll
        for (int r = 0; r < R; r++) {
            #pragma unroll
            for (int b = 0; b < B; b++) {
                acc[r * 8 + b] += wv[r].x * xv[b].x + wv[r].y * xv[b].y +
                                  wv[r].z * xv[b].z + wv[r].w * xv[b].w;
            }
        }
    }

    // Multi-value butterfly fold: 32 accs -> 1 over levels m=1..16; after the
    // fold, lane L (within each 32-lane half) holds acc index (L & 31) summed
    // over its half; one cross-half xor-add completes the 64-lane sum.
    #pragma unroll
    for (int m = 1, n = R * B; m <= 16; m <<= 1, n >>= 1) {
        #pragma unroll
        for (int i = 0; i < 32; i++) {
            if (i < n / 2) {
                const float lo = acc[2 * i];
                const float hi = acc[2 * i + 1];
                const float send = (lane & m) ? lo : hi;
                const float keep = (lane & m) ? hi : lo;
                const float recv = __shfl_xor(send, m, 64);
                acc[i] = keep + recv;
            }
        }
    }
    acc[0] += __shfl_xor(acc[0], 32, 64);  // combine the two halves

    if (lane < 32) {
        const int r = lane >> 3;
        const int b = lane & 7;
        const int row = row0 + r;
        if (row < NNODES) {
            const float z = acc[0] + bias[row];
            sig[(size_t)row * B + b] = 1.f / (1.f + expf(-z));
        }
    }
}

// Kernel 2: out[b*T + t] = prod_{d} sig[paths[ids[b][t]][d] * B + b]
__global__ __launch_bounds__(256) void hsm_prod_kernel(
    const int* __restrict__ ids,    // [B][T]
    const int* __restrict__ paths,  // [V][D]
    const float* __restrict__ sig,  // [NNODES][B]
    float* __restrict__ out)        // [B][T]
{
    const int i = blockIdx.x * blockDim.x + threadIdx.x;
    if (i >= B * T) return;
    const int b = i / T;
    const int id = ids[i];
    const int* p = paths + (size_t)id * D;
    float prod = 1.f;
    #pragma unroll
    for (int d = 0; d < D; d++) {
        prod *= sig[(size_t)p[d] * B + b];
    }
    out[i] = prod;
}

extern "C" void kernel_launch(void* const* d_in, const int* in_sizes, int n_in,
                              void* d_out, int out_size, void* d_ws, size_t ws_size,
                              hipStream_t stream) {
    const float* x     = (const float*)d_in[0];  // [B, DM]
    const int*   ids   = (const int*)d_in[1];    // [B, T]
    const int*   paths = (const int*)d_in[2];    // [V, D]
    const float* W     = (const float*)d_in[3];  // [NNODES, DM]
    const float* bias  = (const float*)d_in[4];  // [NNODES]
    float* out = (float*)d_out;                  // [B, T]
    float* sig = (float*)d_ws;                   // [NNODES, B] = 1 MB scratch

    const int rows_per_block = 4 * R;  // 4 waves x 4 rows = 16
    const int grid1 = (NNODES + rows_per_block - 1) / rows_per_block;  // 2048
    hsm_logits_kernel<<<grid1, 256, 0, stream>>>(x, W, bias, sig);

    const int grid2 = (B * T + 255) / 256;  // 32
    hsm_prod_kernel<<<grid2, 256, 0, stream>>>(ids, paths, sig, out);
}

// Round 4
// 207.963 us; speedup vs baseline: 1.1856x; 1.1856x over previous
//
#include <hip/hip_runtime.h>
#include <math.h>

#define V 32768
#define D 15
#define DM 1024
#define B 8
#define T 1024
#define NNODES (V - 1)  // 32767
#define R 4             // rows per wave

// Kernel 1: sig[v*B + b] = sigmoid(dot(W[v], x[b]) + bias[v]) for all internal nodes v.
// Block = 256 threads (4 waves), R=4 rows/wave -> 16 rows/block, grid = 2048.
// K split across 64 lanes (4 float4 each). x staged in LDS (32 KB); per k-step the
// 8 x-float4 are read once and reused across 4 W rows.
//
// CRITICAL (R3 post-mortem): the reduction must use compile-time-constant acc[]
// indices. A loop-carried (m,n) butterfly defeated full unroll -> acc[] demoted
// to scratch -> 103 MB of spill traffic, kernel at 97 us. The 5 fold levels are
// therefore written out explicitly with literal bounds.
__global__ __launch_bounds__(256, 4) void hsm_logits_kernel(
    const float* __restrict__ x,     // [B][DM]
    const float* __restrict__ W,     // [NNODES][DM]
    const float* __restrict__ bias,  // [NNODES]
    float* __restrict__ sig)         // [NNODES][B]
{
    __shared__ float4 xs[B * DM / 4];  // 2048 float4 = 32 KB, xs[b*256 + u]

    const float4* x4 = (const float4*)x;
    #pragma unroll
    for (int i = threadIdx.x; i < B * DM / 4; i += 256) xs[i] = x4[i];
    __syncthreads();

    const int wave = threadIdx.x >> 6;
    const int lane = threadIdx.x & 63;
    const int row0 = (blockIdx.x * 4 + wave) * R;

    const float4* Wb = (const float4*)W;
    const float4* Wr[R];
    #pragma unroll
    for (int r = 0; r < R; r++) {
        int row = row0 + r;
        if (row > NNODES - 1) row = NNODES - 1;  // clamp (hoisted; store guarded below)
        Wr[r] = Wb + (size_t)row * 256;
    }

    float acc[R * B];  // acc[r*8+b]
    #pragma unroll
    for (int i = 0; i < R * B; i++) acc[i] = 0.f;

    // 256 float4 per row; lane covers u = j*64 + lane for j=0..3.
    #pragma unroll
    for (int j = 0; j < 4; j++) {
        const int u = j * 64 + lane;
        float4 wv[R];
        #pragma unroll
        for (int r = 0; r < R; r++) wv[r] = Wr[r][u];
        float4 xv[B];
        #pragma unroll
        for (int b = 0; b < B; b++) xv[b] = xs[b * 256 + u];
        #pragma unroll
        for (int r = 0; r < R; r++) {
            #pragma unroll
            for (int b = 0; b < B; b++) {
                acc[r * 8 + b] += wv[r].x * xv[b].x + wv[r].y * xv[b].y +
                                  wv[r].z * xv[b].z + wv[r].w * xv[b].w;
            }
        }
    }

    // Multi-value butterfly fold, 32 accs -> 1, explicit levels (constant indices!).
    // After level 5, lane L (within each 32-lane half) holds acc index (L & 31)
    // summed over its half; one cross-half xor-add completes the 64-lane sum.
#define FOLD_LEVEL(MASK, NOUT)                                   \
    _Pragma("unroll")                                            \
    for (int i = 0; i < (NOUT); i++) {                           \
        const float lo = acc[2 * i];                             \
        const float hi = acc[2 * i + 1];                         \
        const float send = (lane & (MASK)) ? lo : hi;            \
        const float keep = (lane & (MASK)) ? hi : lo;            \
        acc[i] = keep + __shfl_xor(send, (MASK), 64);            \
    }
    FOLD_LEVEL(1, 16)
    FOLD_LEVEL(2, 8)
    FOLD_LEVEL(4, 4)
    FOLD_LEVEL(8, 2)
    FOLD_LEVEL(16, 1)
#undef FOLD_LEVEL
    acc[0] += __shfl_xor(acc[0], 32, 64);  // combine the two halves

    if (lane < 32) {
        const int r = lane >> 3;
        const int b = lane & 7;
        const int row = row0 + r;
        if (row < NNODES) {
            const float z = acc[0] + bias[row];
            sig[(size_t)row * B + b] = 1.f / (1.f + expf(-z));
        }
    }
}

// Kernel 2: out[b*T + t] = prod_{d} sig[paths[ids[b][t]][d] * B + b]
__global__ __launch_bounds__(256) void hsm_prod_kernel(
    const int* __restrict__ ids,    // [B][T]
    const int* __restrict__ paths,  // [V][D]
    const float* __restrict__ sig,  // [NNODES][B]
    float* __restrict__ out)        // [B][T]
{
    const int i = blockIdx.x * blockDim.x + threadIdx.x;
    if (i >= B * T) return;
    const int b = i / T;
    const int id = ids[i];
    const int* p = paths + (size_t)id * D;
    float prod = 1.f;
    #pragma unroll
    for (int d = 0; d < D; d++) {
        prod *= sig[(size_t)p[d] * B + b];
    }
    out[i] = prod;
}

extern "C" void kernel_launch(void* const* d_in, const int* in_sizes, int n_in,
                              void* d_out, int out_size, void* d_ws, size_t ws_size,
                              hipStream_t stream) {
    const float* x     = (const float*)d_in[0];  // [B, DM]
    const int*   ids   = (const int*)d_in[1];    // [B, T]
    const int*   paths = (const int*)d_in[2];    // [V, D]
    const float* W     = (const float*)d_in[3];  // [NNODES, DM]
    const float* bias  = (const float*)d_in[4];  // [NNODES]
    float* out = (float*)d_out;                  // [B, T]
    float* sig = (float*)d_ws;                   // [NNODES, B] = 1 MB scratch

    const int rows_per_block = 4 * R;  // 4 waves x 4 rows = 16
    const int grid1 = (NNODES + rows_per_block - 1) / rows_per_block;  // 2048
    hsm_logits_kernel<<<grid1, 256, 0, stream>>>(x, W, bias, sig);

    const int grid2 = (B * T + 255) / 256;  // 32
    hsm_prod_kernel<<<grid2, 256, 0, stream>>>(ids, paths, sig, out);
}